// Round 9
// baseline (9810.452 us; speedup 1.0000x reference)
//
#include <hip/hip_runtime.h>

#define HDIM 128
#define TDIM 2048
#define BDIM 256
#define NT 512
#define RING 32
#define RP 136            // ring pitch in halves (68 dwords ≡ 4 mod 32 -> 2-way max)
#define XGP 17            // xg pitch in dwords (odd -> conflict-free scalar reads)
#define NSTEP (TDIM + 32) // 3-layer pipeline: 2 x 16-step lags

typedef _Float16 half8_t __attribute__((ext_vector_type(8)));
typedef float f32x4 __attribute__((ext_vector_type(4)));

__device__ __forceinline__ f32x4 mfma16(half8_t a, half8_t b, f32x4 c) {
    return __builtin_amdgcn_mfma_f32_16x16x32_f16(a, b, c, 0, 0, 0);
}
// LDS-only barrier (no vmcnt drain): all cross-wave data flows through LDS.
__device__ __forceinline__ void fast_barrier() {
    asm volatile("s_waitcnt lgkmcnt(0)\n\ts_barrier" ::: "memory");
}
// same-wave cross-lane LDS visibility (proj stores -> activation reads)
__device__ __forceinline__ void lds_fence() {
    asm volatile("s_waitcnt lgkmcnt(0)" ::: "memory");
}

__device__ __forceinline__ float sigm_f(float x) { return 1.0f / (1.0f + __expf(-x)); }
__device__ __forceinline__ float tanh_f(float x) { return 1.0f - 2.0f / (1.0f + __expf(2.0f * x)); }

// One-time fp32 -> fp16 weight conversion. Segments of 65536: [Whh0,Wih1,Whh1,Wih2,Whh2]
__global__ __launch_bounds__(256)
void convert_w(const float* __restrict__ Whh0, const float* __restrict__ Wih1,
               const float* __restrict__ Whh1, const float* __restrict__ Wih2,
               const float* __restrict__ Whh2, _Float16* __restrict__ dst) {
    int i = blockIdx.x * 256 + threadIdx.x;
    int seg = i >> 16, off = i & 65535;
    const float* s = (seg == 0) ? Whh0 : (seg == 1) ? Wih1 : (seg == 2) ? Whh1
                   : (seg == 3) ? Wih2 : Whh2;
    dst[i] = (_Float16)s[off];
}

// 2 waves/EU (one 8-wave block per CU) -> 256-VGPR budget: rec weights stay resident.
__global__ __launch_bounds__(NT) __attribute__((amdgpu_waves_per_eu(2, 2)))
void lstm3_kernel(const float* __restrict__ x,   const float* __restrict__ Wih0,
                  const float* __restrict__ bih0, const float* __restrict__ bhh0,
                  const float* __restrict__ bih1, const float* __restrict__ bhh1,
                  const float* __restrict__ bih2, const float* __restrict__ bhh2,
                  const float* __restrict__ fc1w, const float* __restrict__ fc1b,
                  const float* __restrict__ fc2w, const float* __restrict__ fc2b,
                  float* __restrict__ out, const _Float16* __restrict__ wbuf)
{
    __shared__ __align__(16) _Float16 ring_s[3][RING * RP];  // per-layer h rings (~26 KB)
    __shared__ __align__(16) float xg_s[2][512 * XGP];       // L1/L2 input projections (~70 KB)
    __shared__ __align__(16) float xs_s[2][16];              // layer-0 scalar x chunks
    __shared__ __align__(16) float z_s[64];

    const int tid = threadIdx.x, ln = tid & 63, wv = tid >> 6;
    const int n16 = ln & 15, qd = ln >> 4, kb = qd * 8;
    const int b = blockIdx.x;

    // wave -> (segment0, segment1) unit-group assignment; every wave owns exactly 3 groups
    const int s0l_t[8] = {0,0,0,1,1,1,2,2};
    const int s0g_t[8] = {0,3,6,1,4,7,2,5};
    const int s0n_t[8] = {3,3,2,3,3,1,3,3};
    const int s1l_t[8] = {0,0,1,0,0,2,0,0};
    const int s1n_t[8] = {0,0,1,0,0,2,0,0};
    const int s0l = s0l_t[wv], s0g = s0g_t[wv], s0n = s0n_t[wv];
    const int s1l = s1l_t[wv], s1n = s1n_t[wv];

    int slayer[3], sgrp[3];
#pragma unroll
    for (int i = 0; i < 3; ++i) {
        if (i < s0n) { slayer[i] = s0l; sgrp[i] = s0g + i; }
        else         { slayer[i] = s1l; sgrp[i] = i - s0n; }   // seg1 groups start at 0
    }

    const _Float16* whhL0 = wbuf;
    const _Float16* whhL1 = wbuf + 2 * 65536;
    const _Float16* whhL2 = wbuf + 4 * 65536;
    const _Float16* wihL1 = wbuf + 1 * 65536;
    const _Float16* wihL2 = wbuf + 3 * 65536;

    // lane identity: slot = ln/16 (lanes 48-63 idle for activation)
    const int  lslot = (ln < 16) ? 0 : (ln < 32) ? 1 : 2;
    const bool lact  = ln < 48;
    const int  llay  = (lslot == 0) ? slayer[0] : (lslot == 1) ? slayer[1] : slayer[2];
    const int  lgrp  = (lslot == 0) ? sgrp[0]   : (lslot == 1) ? sgrp[1]   : sgrp[2];
    const int  u     = lgrp * 16 + n16;

    float bsum[4], w0g[4];
#pragma unroll
    for (int q = 0; q < 4; ++q) {
        const int row = q * HDIM + u;
        const float* bi = (llay == 0) ? bih0 : (llay == 1) ? bih1 : bih2;
        const float* bh = (llay == 0) ? bhh0 : (llay == 1) ? bhh1 : bhh2;
        bsum[q] = bi[row] + bh[row];
        w0g[q] = (llay == 0) ? Wih0[row] : 0.f;
    }

    // resident recurrent B-fragments: 3 slots x 4 gates x 4 K-blocks (192 VGPRs)
    half8_t bfr[3][4][4];
#pragma unroll
    for (int i = 0; i < 3; ++i) {
        const int lay = slayer[i];
        const _Float16* wp = (lay == 0) ? whhL0 : (lay == 1) ? whhL1 : whhL2;
#pragma unroll
        for (int tau = 0; tau < 4; ++tau) {
            const int row = tau * HDIM + sgrp[i] * 16 + n16;
#pragma unroll
            for (int kk = 0; kk < 4; ++kk)
                bfr[i][tau][kk] = *(const half8_t*)(wp + (size_t)row * HDIM + kk * 32 + kb);
        }
    }

    // zero rings (h(-1)=0 lives in slot 31)
    {
        int* r = (int*)&ring_s[0][0];
        for (int i = tid; i < 3 * RING * RP / 2; i += NT) r[i] = 0;
    }
    // x staging: wave 0 owns it. chunk 0 -> xs_s[0]; chunk 1 -> xpre
    float xpre = 0.f;
    if (wv == 0 && ln < 16) {
        xs_s[0][ln] = x[(size_t)b * TDIM + ln];
        xpre = x[(size_t)b * TDIM + 16 + ln];
    }
    __syncthreads();

    float c_st = 0.f;
    float g4[3][4];

#pragma unroll 1
    for (int s = 0; s < NSTEP; ++s) {
        fast_barrier();

        // ---- x chunk handoff (w0): publish chunk c+1 at the last step of chunk c ----
        if (wv == 0 && (s & 15) == 15 && s < TDIM - 1 && ln < 16) {
            xs_s[((s >> 4) + 1) & 1][ln] = xpre;
            int t = s + 17 + ln;
            xpre = x[(size_t)b * TDIM + (t < TDIM ? t : 0)];
        }

        // ---- projection GEMMs (chunk starts; wave-uniform) ----
#pragma unroll
        for (int pseg = 0; pseg < 2; ++pseg) {
            const int pl  = (pseg == 0) ? s0l : s1l;
            const int pg0 = (pseg == 0) ? s0g : 0;
            const int pn  = (pseg == 0) ? s0n : s1n;
            const bool en = (pseg == 0) ? (s0l >= 1) : (s1n > 0);
            if (!en) continue;
            const int tl = s - 16 * pl;
            if (tl < 0 || tl >= TDIM || (tl & 15) != 0) continue;

            const _Float16* ringp = &ring_s[pl - 1][0];
            half8_t aP[4];
            const int srow = ((tl + n16) & 31) * RP;     // A row m = timestep
#pragma unroll
            for (int kk = 0; kk < 4; ++kk)
                aP[kk] = *(const half8_t*)(ringp + srow + kk * 32 + kb);
            const _Float16* wp = (pl == 1) ? wihL1 : wihL2;
            float* xgb = &xg_s[pl - 1][0];
#pragma unroll 1
            for (int g = 0; g < pn; ++g) {
#pragma unroll
                for (int tau = 0; tau < 4; ++tau) {
                    const int gp = tau * HDIM + (pg0 + g) * 16 + n16;
                    const _Float16* wr = wp + (size_t)gp * HDIM + kb;
                    half8_t b0 = *(const half8_t*)(wr);
                    half8_t b1 = *(const half8_t*)(wr + 32);
                    half8_t b2 = *(const half8_t*)(wr + 64);
                    half8_t b3 = *(const half8_t*)(wr + 96);
                    f32x4 a = {0.f, 0.f, 0.f, 0.f};
                    a = mfma16(aP[0], b0, a);
                    a = mfma16(aP[1], b1, a);
                    a = mfma16(aP[2], b2, a);
                    a = mfma16(aP[3], b3, a);
                    float* dst = xgb + gp * XGP + qd * 4;   // C row = qd*4+reg = timestep
                    dst[0] = a[0]; dst[1] = a[1]; dst[2] = a[2]; dst[3] = a[3];
                }
            }
        }
        lds_fence();   // proj stores visible to this wave's activation reads

        // ---- recurrent MFMA per slot (A broadcast: all M-rows = h(t-1)) ----
        {
            half8_t aR[4];
            int curlay = -1;
#pragma unroll
            for (int i = 0; i < 3; ++i) {
                const int lay = slayer[i];
                const int tl = s - 16 * lay;
                if (tl >= 0 && tl < TDIM) {
                    if (lay != curlay) {
                        const _Float16* rp = &ring_s[lay][((tl - 1) & 31) * RP];
#pragma unroll
                        for (int kk = 0; kk < 4; ++kk)
                            aR[kk] = *(const half8_t*)(rp + kk * 32 + kb);
                        curlay = lay;
                    }
#pragma unroll
                    for (int tau = 0; tau < 4; ++tau) {
                        f32x4 a = {0.f, 0.f, 0.f, 0.f};
                        a = mfma16(aR[0], bfr[i][tau][0], a);
                        a = mfma16(aR[1], bfr[i][tau][1], a);
                        a = mfma16(aR[2], bfr[i][tau][2], a);
                        a = mfma16(aR[3], bfr[i][tau][3], a);
                        g4[i][tau] = a[0];   // all C rows identical
                    }
                }
            }
        }

        // ---- activation + h write (per lane) ----
        {
            const int tl_l = s - 16 * llay;
            if (lact && tl_l >= 0 && tl_l < TDIM) {
                float ga[4];
#pragma unroll
                for (int q = 0; q < 4; ++q)
                    ga[q] = (lslot == 0) ? g4[0][q] : (lslot == 1) ? g4[1][q] : g4[2][q];
                float xq[4];
                if (llay == 0) {
                    float xt = xs_s[(tl_l >> 4) & 1][tl_l & 15];
#pragma unroll
                    for (int q = 0; q < 4; ++q) xq[q] = xt * w0g[q];
                } else {
                    const float* xgb = &xg_s[llay - 1][0];
#pragma unroll
                    for (int q = 0; q < 4; ++q)
                        xq[q] = xgb[(q * HDIM + u) * XGP + (tl_l & 15)];
                }
                float ig = sigm_f(ga[0] + xq[0] + bsum[0]);
                float fg = sigm_f(ga[1] + xq[1] + bsum[1]);
                float gg = tanh_f(ga[2] + xq[2] + bsum[2]);
                float og = sigm_f(ga[3] + xq[3] + bsum[3]);
                c_st = fg * c_st + ig * gg;
                float h = og * tanh_f(c_st);
                ring_s[llay][(tl_l & 31) * RP + u] = (_Float16)h;
            }
        }
    }

    // ---- FC head: h_T of layer 2 = ring slot 2047&31 = 31 ----
    __syncthreads();
    if (tid < 64) {
        const float* w = fc1w + tid * HDIM;
        float sacc = fc1b[tid];
#pragma unroll
        for (int k = 0; k < HDIM; ++k) sacc += w[k] * (float)ring_s[2][31 * RP + k];
        z_s[tid] = fmaxf(sacc, 0.0f);
    }
    __syncthreads();
    if (tid < 5) {
        const float* w = fc2w + tid * 64;
        float sacc = fc2b[tid];
#pragma unroll
        for (int k = 0; k < 64; ++k) sacc += w[k] * z_s[k];
        out[b * 5 + tid] = sacc;
    }
}

extern "C" void kernel_launch(void* const* d_in, const int* in_sizes, int n_in,
                              void* d_out, int out_size, void* d_ws, size_t ws_size,
                              hipStream_t stream) {
    (void)in_sizes; (void)n_in; (void)out_size; (void)ws_size;
    const float* x    = (const float*)d_in[0];
    const float* Wih0 = (const float*)d_in[1];
    const float* Whh0 = (const float*)d_in[2];
    const float* bih0 = (const float*)d_in[3];
    const float* bhh0 = (const float*)d_in[4];
    const float* Wih1 = (const float*)d_in[5];
    const float* Whh1 = (const float*)d_in[6];
    const float* bih1 = (const float*)d_in[7];
    const float* bhh1 = (const float*)d_in[8];
    const float* Wih2 = (const float*)d_in[9];
    const float* Whh2 = (const float*)d_in[10];
    const float* bih2 = (const float*)d_in[11];
    const float* bhh2 = (const float*)d_in[12];
    const float* fc1w = (const float*)d_in[13];
    const float* fc1b = (const float*)d_in[14];
    const float* fc2w = (const float*)d_in[15];
    const float* fc2b = (const float*)d_in[16];
    float* out = (float*)d_out;

    _Float16* wbuf = (_Float16*)d_ws;   // fp16 weights (640 KB)

    hipLaunchKernelGGL(convert_w, dim3(1280), dim3(256), 0, stream,
                       Whh0, Wih1, Whh1, Wih2, Whh2, wbuf);
    hipLaunchKernelGGL(lstm3_kernel, dim3(BDIM), dim3(NT), 0, stream,
                       x, Wih0, bih0, bhh0, bih1, bhh1, bih2, bhh2,
                       fc1w, fc1b, fc2w, fc2b, out, wbuf);
}

// Round 10
// 4576.538 us; speedup vs baseline: 2.1436x; 2.1436x over previous
//
#include <hip/hip_runtime.h>

#define HDIM 128
#define TDIM 2048
#define BDIM 256
#define NT 512
#define RING 32
#define RP 136            // ring pitch in halves
#define XGP 17            // phase-1 xg pitch (dwords)
#define XGP2 20           // phase-2 xg pitch (dwords)
#define CHUNK 16

typedef _Float16 half8_t __attribute__((ext_vector_type(8)));
typedef float f32x4 __attribute__((ext_vector_type(4)));

__device__ __forceinline__ f32x4 mfma16(half8_t a, half8_t b, f32x4 c) {
    return __builtin_amdgcn_mfma_f32_16x16x32_f16(a, b, c, 0, 0, 0);
}
// MFMA with B forced into AGPRs (D==C tied). Residency in AGPR is mandatory:
// asm cannot be rematerialized, so the weights stay in the acc file.
__device__ __forceinline__ void mfma_accA(f32x4 &d, half8_t a, half8_t b) {
    asm("v_mfma_f32_16x16x32_f16 %0, %1, %2, %0" : "+v"(d) : "v"(a), "a"(b));
}
__device__ __forceinline__ void pin_agpr(half8_t &v) { asm("" : "+a"(v)); }

__device__ __forceinline__ void fast_barrier() {
    asm volatile("s_waitcnt lgkmcnt(0)\n\ts_barrier" ::: "memory");
}
__device__ __forceinline__ void lds_fence() {
    asm volatile("s_waitcnt lgkmcnt(0)" ::: "memory");
}

__device__ __forceinline__ float sigm_f(float x) { return 1.0f / (1.0f + __expf(-x)); }
__device__ __forceinline__ float tanh_f(float x) { return 1.0f - 2.0f / (1.0f + __expf(2.0f * x)); }

// One-time fp32 -> fp16 weight conversion. Segments of 65536: [Whh0,Wih1,Whh1,Wih2,Whh2]
__global__ __launch_bounds__(256)
void convert_w(const float* __restrict__ Whh0, const float* __restrict__ Wih1,
               const float* __restrict__ Whh1, const float* __restrict__ Wih2,
               const float* __restrict__ Whh2, _Float16* __restrict__ dst) {
    int i = blockIdx.x * 256 + threadIdx.x;
    int seg = i >> 16, off = i & 65535;
    const float* s = (seg == 0) ? Whh0 : (seg == 1) ? Wih1 : (seg == 2) ? Whh1
                   : (seg == 3) ? Wih2 : Whh2;
    dst[i] = (_Float16)s[off];
}

__global__ __launch_bounds__(NT, 2)
void lstm3_kernel(const float* __restrict__ x,   const float* __restrict__ Wih0,
                  const float* __restrict__ bih0, const float* __restrict__ bhh0,
                  const float* __restrict__ bih1, const float* __restrict__ bhh1,
                  const float* __restrict__ bih2, const float* __restrict__ bhh2,
                  const float* __restrict__ fc1w, const float* __restrict__ fc1b,
                  const float* __restrict__ fc2w, const float* __restrict__ fc2b,
                  float* __restrict__ out,
                  _Float16* __restrict__ gbuf, const _Float16* __restrict__ wbuf)
{
    __shared__ __align__(16) _Float16 ring_s[2][RING * RP];   // L0/L1 h rings
    __shared__ __align__(16) float xg1_s[512 * XGP];          // L1 input projections
    __shared__ __align__(16) float xs_s[2][16];               // layer-0 x chunks
    __shared__ __align__(16) _Float16 hwin_s[CHUNK][HDIM];    // phase-2 h window
    __shared__ __align__(16) _Float16 xin_s[2][CHUNK][HDIM];  // phase-2 staged chunks
    __shared__ __align__(16) float xg2_s[2][512 * XGP2];      // phase-2 projections
    __shared__ __align__(16) float z_s[64];

    const int tid = threadIdx.x, ln = tid & 63, wv = tid >> 6;
    const int n16 = ln & 15, qd = ln >> 4, kb = qd * 8;
    const int un = wv * 16 + n16;
    const int b = blockIdx.x;

    const _Float16* whhL0 = wbuf;
    const _Float16* wihL1 = wbuf + 1 * 65536;
    const _Float16* whhL1 = wbuf + 2 * 65536;
    const _Float16* wihL2 = wbuf + 3 * 65536;
    const _Float16* whhL2 = wbuf + 4 * 65536;

    // ================= phase 1: layers 0+1 pipelined (lag 16) =================
    {
        float bsum0[4], bsum1[4], w0[4];
#pragma unroll
        for (int q = 0; q < 4; ++q) {
            const int row = q * HDIM + un;
            bsum0[q] = bih0[row] + bhh0[row];
            bsum1[q] = bih1[row] + bhh1[row];
            w0[q] = Wih0[row];
        }
        half8_t wf0[4][4], wf1[4][4];   // rec B-frags, AGPR-pinned (128 AGPRs)
#pragma unroll
        for (int tau = 0; tau < 4; ++tau) {
            const int row = tau * HDIM + un;
#pragma unroll
            for (int kk = 0; kk < 4; ++kk) {
                wf0[tau][kk] = *(const half8_t*)(whhL0 + (size_t)row * HDIM + kk * 32 + kb);
                wf1[tau][kk] = *(const half8_t*)(whhL1 + (size_t)row * HDIM + kk * 32 + kb);
                pin_agpr(wf0[tau][kk]);
                pin_agpr(wf1[tau][kk]);
            }
        }
        for (int i = tid; i < 2 * RING * RP / 2; i += NT) ((int*)&ring_s[0][0])[i] = 0;
        float xpre = 0.f;
        if (wv == 0 && ln < 16) {
            xs_s[0][ln] = x[(size_t)b * TDIM + ln];
            xpre = x[(size_t)b * TDIM + 16 + ln];
        }
        __syncthreads();

        float c0 = 0.f, c1 = 0.f;
#pragma unroll 1
        for (int s = 0; s < TDIM + 16; ++s) {
            fast_barrier();
            // x chunk publish (wave 0)
            if (wv == 0 && (s & 15) == 15 && s < TDIM - 1 && ln < 16) {
                xs_s[((s >> 4) + 1) & 1][ln] = xpre;
                int t = s + 17 + ln;
                xpre = x[(size_t)b * TDIM + (t < TDIM ? t : 0)];
            }
            // L1 projection GEMM at chunk starts: rows t = s-16 .. s-1 of ring0
            if ((s & 15) == 0 && s >= 16) {
                const int tb = s - 16;
                const _Float16* r0 = &ring_s[0][((tb + n16) & 31) * RP];
                half8_t aP0 = *(const half8_t*)(r0 + kb);
                half8_t aP1 = *(const half8_t*)(r0 + 32 + kb);
                half8_t aP2 = *(const half8_t*)(r0 + 64 + kb);
                half8_t aP3 = *(const half8_t*)(r0 + 96 + kb);
#pragma unroll 1
                for (int tau = 0; tau < 4; ++tau) {
                    const _Float16* wr = wihL1 + (size_t)(tau * HDIM + un) * HDIM + kb;
                    half8_t b0 = *(const half8_t*)(wr);
                    half8_t b1 = *(const half8_t*)(wr + 32);
                    half8_t b2 = *(const half8_t*)(wr + 64);
                    half8_t b3 = *(const half8_t*)(wr + 96);
                    f32x4 a = {0.f, 0.f, 0.f, 0.f};
                    a = mfma16(aP0, b0, a);
                    a = mfma16(aP1, b1, a);
                    a = mfma16(aP2, b2, a);
                    a = mfma16(aP3, b3, a);
                    *(f32x4*)&xg1_s[(tau * HDIM + un) * XGP + qd * 4] = a;
                }
            }
            lds_fence();   // own proj stores visible to own act reads
            float xq1[4];
            if (s >= 16) {
                const int ti = (s - 16) & 15;
#pragma unroll
                for (int q = 0; q < 4; ++q) xq1[q] = xg1_s[(q * HDIM + un) * XGP + ti];
            }

            // rec MFMAs (A-broadcast), B from AGPRs
            f32x4 d0[4], d1[4];
            if (s < TDIM) {
                const _Float16* rp = &ring_s[0][((s - 1) & 31) * RP];
                half8_t A0 = *(const half8_t*)(rp + kb);
                half8_t A1 = *(const half8_t*)(rp + 32 + kb);
                half8_t A2 = *(const half8_t*)(rp + 64 + kb);
                half8_t A3 = *(const half8_t*)(rp + 96 + kb);
#pragma unroll
                for (int tau = 0; tau < 4; ++tau) {
                    d0[tau] = (f32x4){0.f, 0.f, 0.f, 0.f};
                    mfma_accA(d0[tau], A0, wf0[tau][0]);
                    mfma_accA(d0[tau], A1, wf0[tau][1]);
                    mfma_accA(d0[tau], A2, wf0[tau][2]);
                    mfma_accA(d0[tau], A3, wf0[tau][3]);
                }
            }
            if (s >= 16) {
                const _Float16* rp = &ring_s[1][((s - 17) & 31) * RP];
                half8_t A0 = *(const half8_t*)(rp + kb);
                half8_t A1 = *(const half8_t*)(rp + 32 + kb);
                half8_t A2 = *(const half8_t*)(rp + 64 + kb);
                half8_t A3 = *(const half8_t*)(rp + 96 + kb);
#pragma unroll
                for (int tau = 0; tau < 4; ++tau) {
                    d1[tau] = (f32x4){0.f, 0.f, 0.f, 0.f};
                    mfma_accA(d1[tau], A0, wf1[tau][0]);
                    mfma_accA(d1[tau], A1, wf1[tau][1]);
                    mfma_accA(d1[tau], A2, wf1[tau][2]);
                    mfma_accA(d1[tau], A3, wf1[tau][3]);
                }
            }
            asm volatile("s_nop 7\n\ts_nop 7" ::);   // MFMA D -> VALU read hazard pad

            if (s < TDIM) {
                float xt = xs_s[(s >> 4) & 1][s & 15];
                float gi = sigm_f(d0[0][0] + xt * w0[0] + bsum0[0]);
                float gf = sigm_f(d0[1][0] + xt * w0[1] + bsum0[1]);
                float gg = tanh_f(d0[2][0] + xt * w0[2] + bsum0[2]);
                float go = sigm_f(d0[3][0] + xt * w0[3] + bsum0[3]);
                c0 = gf * c0 + gi * gg;
                if (kb == 0) ring_s[0][(s & 31) * RP + un] = (_Float16)(go * tanh_f(c0));
            }
            if (s >= 16) {
                float gi = sigm_f(d1[0][0] + xq1[0] + bsum1[0]);
                float gf = sigm_f(d1[1][0] + xq1[1] + bsum1[1]);
                float gg = tanh_f(d1[2][0] + xq1[2] + bsum1[2]);
                float go = sigm_f(d1[3][0] + xq1[3] + bsum1[3]);
                c1 = gf * c1 + gi * gg;
                if (kb == 0) ring_s[1][((s - 16) & 31) * RP + un] = (_Float16)(go * tanh_f(c1));
            }
            // flush completed L1 chunk to gbuf
            if ((s & 15) == 15 && s >= 31) {
                fast_barrier();
                const int ci = (s - 16) >> 4;
                const int r = tid >> 5, col = (tid & 31) * 4;
                *(int2*)(gbuf + ((size_t)b * TDIM + ci * 16 + r) * HDIM + col) =
                    *(const int2*)(&ring_s[1][((ci & 1) * 16 + r) * RP + col]);
            }
        }
    }
    __syncthreads();   // REAL barrier: drain gbuf stores before phase-2 reads

    // ================= phase 2: layer 2 (R7 proven structure) =================
    {
        float bsum[4];
        half8_t bhhf[4][4], bihf[4][4];
#pragma unroll
        for (int tau = 0; tau < 4; ++tau) {
            const int g = tau * HDIM + un;
            bsum[tau] = bih2[g] + bhh2[g];
#pragma unroll
            for (int kk = 0; kk < 4; ++kk)
                bhhf[tau][kk] = *(const half8_t*)(whhL2 + (size_t)g * HDIM + kk * 32 + kb);
            const int gp = (wv * 4 + tau) * 16 + n16;
#pragma unroll
            for (int kk = 0; kk < 4; ++kk)
                bihf[tau][kk] = *(const half8_t*)(wihL2 + (size_t)gp * HDIM + kk * 32 + kb);
        }
        if (tid < HDIM) hwin_s[CHUNK - 1][tid] = (_Float16)0.f;
        float c = 0.f;

        int2 stage = ((const int2*)(gbuf + (size_t)b * TDIM * HDIM))[tid];
        ((int2*)&xin_s[0][0][0])[tid] = stage;
        __syncthreads();
        {
            half8_t A0 = *(const half8_t*)&xin_s[0][n16][kb];
            half8_t A1 = *(const half8_t*)&xin_s[0][n16][32 + kb];
            half8_t A2 = *(const half8_t*)&xin_s[0][n16][64 + kb];
            half8_t A3 = *(const half8_t*)&xin_s[0][n16][96 + kb];
#pragma unroll
            for (int tau = 0; tau < 4; ++tau) {
                f32x4 a = {0.f, 0.f, 0.f, 0.f};
                a = mfma16(A0, bihf[tau][0], a);
                a = mfma16(A1, bihf[tau][1], a);
                a = mfma16(A2, bihf[tau][2], a);
                a = mfma16(A3, bihf[tau][3], a);
                const int g = (wv * 4 + tau) * 16 + n16;
                *(f32x4*)&xg2_s[0][g * XGP2 + (kb >> 1)] = a;
            }
        }
        stage = ((const int2*)(gbuf + ((size_t)b * TDIM + CHUNK) * HDIM))[tid];

        f32x4 pacc[4];
#pragma unroll 1
        for (int t0 = 0; t0 < TDIM; t0 += CHUNK) {
            const int ci = t0 >> 4, rbuf = ci & 1, cb = rbuf ^ 1;
            ((int2*)&xin_s[cb][0][0])[tid] = stage;
            int tn = (t0 + 2 * CHUNK < TDIM) ? (t0 + 2 * CHUNK) : t0;
            stage = ((const int2*)(gbuf + ((size_t)b * TDIM + tn) * HDIM))[tid];

            float2 xgv[4];
#pragma unroll
            for (int tt = 0; tt < CHUNK; ++tt) {
                fast_barrier();
                const int t = t0 + tt, row = (t + CHUNK - 1) & 15;
                half8_t A0 = *(const half8_t*)&hwin_s[row][kb];
                half8_t A1 = *(const half8_t*)&hwin_s[row][32 + kb];
                half8_t A2 = *(const half8_t*)&hwin_s[row][64 + kb];
                half8_t A3 = *(const half8_t*)&hwin_s[row][96 + kb];

                if (tt == 0) {
                    half8_t X0 = *(const half8_t*)&xin_s[cb][n16][kb];
                    half8_t X1 = *(const half8_t*)&xin_s[cb][n16][32 + kb];
                    half8_t X2 = *(const half8_t*)&xin_s[cb][n16][64 + kb];
                    half8_t X3 = *(const half8_t*)&xin_s[cb][n16][96 + kb];
#pragma unroll
                    for (int tau = 0; tau < 4; ++tau) {
                        f32x4 a = {0.f, 0.f, 0.f, 0.f};
                        a = mfma16(X0, bihf[tau][0], a);
                        a = mfma16(X1, bihf[tau][1], a);
                        a = mfma16(X2, bihf[tau][2], a);
                        a = mfma16(X3, bihf[tau][3], a);
                        pacc[tau] = a;
                    }
                }
                if ((tt & 1) == 0) {
#pragma unroll
                    for (int q = 0; q < 4; ++q)
                        xgv[q] = *(const float2*)&xg2_s[rbuf][(q * HDIM + un) * XGP2 + tt];
                }

                float g4[4];
#pragma unroll
                for (int tau = 0; tau < 4; ++tau) {
                    f32x4 Cz = {0.f, 0.f, 0.f, 0.f};
                    Cz = mfma16(A0, bhhf[tau][0], Cz);
                    Cz = mfma16(A1, bhhf[tau][1], Cz);
                    Cz = mfma16(A2, bhhf[tau][2], Cz);
                    Cz = mfma16(A3, bhhf[tau][3], Cz);
                    g4[tau] = Cz[0];
                }

                float x0 = (tt & 1) ? xgv[0].y : xgv[0].x;
                float x1 = (tt & 1) ? xgv[1].y : xgv[1].x;
                float x2 = (tt & 1) ? xgv[2].y : xgv[2].x;
                float x3 = (tt & 1) ? xgv[3].y : xgv[3].x;
                float ig = sigm_f(g4[0] + x0 + bsum[0]);
                float fg = sigm_f(g4[1] + x1 + bsum[1]);
                float gg = tanh_f(g4[2] + x2 + bsum[2]);
                float og = sigm_f(g4[3] + x3 + bsum[3]);
                c = fg * c + ig * gg;
                if (kb == 0) hwin_s[t & 15][un] = (_Float16)(og * tanh_f(c));

                if (tt == CHUNK - 1) {
#pragma unroll
                    for (int tau = 0; tau < 4; ++tau) {
                        const int g = (wv * 4 + tau) * 16 + n16;
                        *(f32x4*)&xg2_s[cb][g * XGP2 + (kb >> 1)] = pacc[tau];
                    }
                }
            }
        }
    }

    // ---- FC head: final h (t=2047) is hwin_s[15] ----
    __syncthreads();
    if (tid < 64) {
        const float* w = fc1w + tid * HDIM;
        float sacc = fc1b[tid];
#pragma unroll
        for (int k = 0; k < HDIM; ++k) sacc += w[k] * (float)hwin_s[CHUNK - 1][k];
        z_s[tid] = fmaxf(sacc, 0.0f);
    }
    __syncthreads();
    if (tid < 5) {
        const float* w = fc2w + tid * 64;
        float sacc = fc2b[tid];
#pragma unroll
        for (int k = 0; k < 64; ++k) sacc += w[k] * z_s[k];
        out[b * 5 + tid] = sacc;
    }
}

extern "C" void kernel_launch(void* const* d_in, const int* in_sizes, int n_in,
                              void* d_out, int out_size, void* d_ws, size_t ws_size,
                              hipStream_t stream) {
    (void)in_sizes; (void)n_in; (void)out_size; (void)ws_size;
    const float* x    = (const float*)d_in[0];
    const float* Wih0 = (const float*)d_in[1];
    const float* Whh0 = (const float*)d_in[2];
    const float* bih0 = (const float*)d_in[3];
    const float* bhh0 = (const float*)d_in[4];
    const float* Wih1 = (const float*)d_in[5];
    const float* Whh1 = (const float*)d_in[6];
    const float* bih1 = (const float*)d_in[7];
    const float* bhh1 = (const float*)d_in[8];
    const float* Wih2 = (const float*)d_in[9];
    const float* Whh2 = (const float*)d_in[10];
    const float* bih2 = (const float*)d_in[11];
    const float* bhh2 = (const float*)d_in[12];
    const float* fc1w = (const float*)d_in[13];
    const float* fc1b = (const float*)d_in[14];
    const float* fc2w = (const float*)d_in[15];
    const float* fc2b = (const float*)d_in[16];
    float* out = (float*)d_out;

    _Float16* gbuf = (_Float16*)d_ws;                 // 128 MB inter-phase buffer
    _Float16* wbuf = gbuf + (size_t)67108864;         // fp16 weights (640 KB)

    hipLaunchKernelGGL(convert_w, dim3(1280), dim3(256), 0, stream,
                       Whh0, Wih1, Whh1, Wih2, Whh2, wbuf);
    hipLaunchKernelGGL(lstm3_kernel, dim3(BDIM), dim3(NT), 0, stream,
                       x, Wih0, bih0, bhh0, bih1, bhh1, bih2, bhh2,
                       fc1w, fc1b, fc2w, fc2b, out, gbuf, wbuf);
}